// Round 1
// baseline (631.008 us; speedup 1.0000x reference)
//
#include <hip/hip_runtime.h>

#define S_TOK 8192
#define H_DIM 1024
#define NE    8
#define CAP   1024
#define DFF   4096

typedef unsigned short u16;
typedef __bf16 bf16_t;
typedef bf16_t bf16x8 __attribute__((ext_vector_type(8)));
typedef float  f32x4  __attribute__((ext_vector_type(4)));

__device__ __forceinline__ u16 f2bf(float f) {
  union { float f; unsigned u; } a; a.f = f;
  unsigned u = a.u;
  u += 0x7fffu + ((u >> 16) & 1u);   // RNE
  return (u16)(u >> 16);
}

__device__ __forceinline__ float gelu_tanh(float x) {
  const float c = 0.7978845608028654f;
  float t = tanhf(c * (x + 0.044715f * x * x * x));
  return 0.5f * x * (1.0f + t);
}

// ---------------- gating: logits, softmax, argmax, per-block rank/histogram ----------
__global__ void gate_kernel(const float* __restrict__ x, const float* __restrict__ wg,
                            float* __restrict__ gate, int* __restrict__ expert,
                            int* __restrict__ rank, int* __restrict__ blockCnt,
                            float* __restrict__ blockMe) {
  __shared__ float sg[16][8];
  __shared__ int   se[16];
  int tid = threadIdx.x, lane = tid & 63, w = tid >> 6;
  int b = blockIdx.x;
  for (int j = 0; j < 4; ++j) {
    int t = w * 4 + j;
    int s = b * 16 + t;
    const float* xr = x + (size_t)s * H_DIM;
    float acc[8];
#pragma unroll
    for (int e = 0; e < 8; ++e) acc[e] = 0.f;
#pragma unroll
    for (int i = 0; i < 16; ++i) {
      int h = i * 64 + lane;
      float xv = xr[h];
      float4 wa = *(const float4*)(wg + h * 8);
      float4 wb = *(const float4*)(wg + h * 8 + 4);
      acc[0] += xv * wa.x; acc[1] += xv * wa.y; acc[2] += xv * wa.z; acc[3] += xv * wa.w;
      acc[4] += xv * wb.x; acc[5] += xv * wb.y; acc[6] += xv * wb.z; acc[7] += xv * wb.w;
    }
#pragma unroll
    for (int off = 32; off >= 1; off >>= 1)
#pragma unroll
      for (int e = 0; e < 8; ++e) acc[e] += __shfl_down(acc[e], off);
    if (lane == 0) {
      float mx = acc[0];
#pragma unroll
      for (int e = 1; e < 8; ++e) mx = fmaxf(mx, acc[e]);
      float g[8], Z = 0.f;
#pragma unroll
      for (int e = 0; e < 8; ++e) { g[e] = expf(acc[e] - mx); Z += g[e]; }
      int am = 0; float best = acc[0];
#pragma unroll
      for (int e = 1; e < 8; ++e) if (acc[e] > best) { best = acc[e]; am = e; }
      float inv = 1.f / Z;
#pragma unroll
      for (int e = 0; e < 8; ++e) sg[t][e] = g[e] * inv;
      se[t] = am;
      gate[s] = g[am] * inv;
      expert[s] = am;
    }
  }
  __syncthreads();
  if (tid < 16) {
    int e = se[tid], r = 0;
    for (int t2 = 0; t2 < tid; ++t2) r += (se[t2] == e) ? 1 : 0;
    rank[b * 16 + tid] = r;
  }
  if (tid < 8) {
    int c = 0; float m = 0.f;
#pragma unroll
    for (int t = 0; t < 16; ++t) { c += (se[t] == tid) ? 1 : 0; m += sg[t][tid]; }
    blockCnt[b * 8 + tid] = c;
    blockMe[b * 8 + tid] = m;
  }
}

// ------------- scan over 512 block histograms; l_aux + exp_counts to out tail --------
__global__ void scan_kernel(const int* __restrict__ blockCnt, const float* __restrict__ blockMe,
                            int* __restrict__ blockOff, int* __restrict__ counts,
                            float* __restrict__ tail) {
  int tid = threadIdx.x;
  int e = tid >> 6, lane = tid & 63;   // one wave per expert
  int run = 0; float msum = 0.f;
  for (int c = 0; c < 8; ++c) {
    int b = c * 64 + lane;
    int v = blockCnt[b * 8 + e];
    float mv = blockMe[b * 8 + e];
    int sc = v;
#pragma unroll
    for (int off = 1; off < 64; off <<= 1) {
      int u = __shfl_up(sc, off);
      if (lane >= off) sc += u;
    }
    blockOff[b * 8 + e] = run + sc - v;
    run += __shfl(sc, 63);
#pragma unroll
    for (int off = 32; off >= 1; off >>= 1) mv += __shfl_down(mv, off);
    msum += __shfl(mv, 0);
  }
  __shared__ float sm[8];
  __shared__ int scnt[8];
  if (lane == 0) {
    sm[e] = msum; scnt[e] = run;
    counts[e] = run < CAP ? run : CAP;
  }
  __syncthreads();
  if (tid == 0) {
    float la = 0.f;
    for (int i = 0; i < 8; ++i)
      la += (sm[i] / (float)S_TOK) * ((float)scnt[i] / (float)S_TOK);
    tail[0] = la * (float)NE;
    for (int i = 0; i < 8; ++i) {
      int cc = scnt[i] < CAP ? scnt[i] : CAP;
      tail[1 + i] = (float)cc;
    }
  }
}

// ---------------- slot assignment ----------------------------------------------------
__global__ void assign_kernel(const int* __restrict__ expert, const int* __restrict__ rank,
                              const int* __restrict__ blockOff, int* __restrict__ slot_token) {
  int s = blockIdx.x * 256 + threadIdx.x;
  int e = expert[s];
  int pos = blockOff[(s >> 4) * 8 + e] + rank[s];
  if (pos < CAP) slot_token[e * CAP + pos] = s;
}

// ---------------- gather tokens into expert slots (fp32 -> bf16) ---------------------
__global__ void gather_kernel(const float* __restrict__ x, const int* __restrict__ slot_token,
                              const int* __restrict__ counts, u16* __restrict__ disp) {
  int slot = blockIdx.x;
  int e = slot >> 10, c = slot & 1023;
  int t = threadIdx.x;
  ushort4 v4;
  if (c < counts[e]) {
    int s = slot_token[slot];
    float4 v = *(const float4*)(x + (size_t)s * H_DIM + t * 4);
    v4.x = f2bf(v.x); v4.y = f2bf(v.y); v4.z = f2bf(v.z); v4.w = f2bf(v.w);
  } else {
    v4.x = 0; v4.y = 0; v4.z = 0; v4.w = 0;
  }
  *(ushort4*)(disp + (size_t)slot * H_DIM + t * 4) = v4;
}

// ---------------- transpose + fp32->bf16 convert: src[R][C] -> dst[C][R] -------------
__global__ void transpose_convert(const float* __restrict__ src0, u16* __restrict__ dst0,
                                  int R, int C) {
  __shared__ float tile[32][33];
  int e = blockIdx.z;
  const float* src = src0 + (size_t)e * R * C;
  u16* dst = dst0 + (size_t)e * R * C;
  int c0 = blockIdx.x * 32, r0 = blockIdx.y * 32;
  int xq = threadIdx.x & 31, yq = threadIdx.x >> 5;
#pragma unroll
  for (int i = 0; i < 32; i += 8)
    tile[yq + i][xq] = src[(size_t)(r0 + yq + i) * C + c0 + xq];
  __syncthreads();
#pragma unroll
  for (int i = 0; i < 32; i += 8)
    dst[(size_t)(c0 + yq + i) * R + r0 + xq] = f2bf(tile[xq][yq + i]);
}

// ---------------- GEMM core: 128x128 tile, BK=32, 4 waves, m97 structure -------------
// LDS layout: per tile row (32 bf16 = 4 x 16B chunks), chunk slot = kq ^ ((row>>1)&3)
// -> ds_read_b128 fragment reads are 2-way conflict (free).
__device__ __forceinline__ void stage_tile(const u16* g, int ldk, u16* lds) {
  int tid = threadIdx.x;
  int lane = tid & 63, w = tid >> 6;
#pragma unroll
  for (int r = 0; r < 2; ++r) {
    int p = (w * 2 + r) * 64 + lane;      // physical 16B chunk 0..511
    int row = p >> 2;
    int kq = (p & 3) ^ ((row >> 1) & 3);  // logical k-chunk stored at this slot
    const u16* gp = g + (size_t)row * ldk + kq * 8;
    u16* lp = lds + (w * 2 + r) * 512;    // wave-uniform base; HW adds lane*16B
    __builtin_amdgcn_global_load_lds((__attribute__((address_space(1))) int*)(gp),
                                     (__attribute__((address_space(3))) int*)(lp),
                                     16, 0, 0);
  }
}

template <int KDIM>
__device__ __forceinline__ void gemm_core(const u16* A, const u16* Bt, int lda, int ldb,
                                          u16* As, u16* Bs, f32x4 acc[4][4]) {
  int tid = threadIdx.x;
  int lane = tid & 63;
  int w = tid >> 6, wm = w >> 1, wn = w & 1;
  int q = lane >> 4, l15 = lane & 15;
  int aoff[4], boff[4];
#pragma unroll
  for (int t = 0; t < 4; ++t) {
    int ra = wm * 64 + t * 16 + l15;
    aoff[t] = ra * 32 + ((q ^ ((ra >> 1) & 3)) * 8);
    int rb = wn * 64 + t * 16 + l15;
    boff[t] = rb * 32 + ((q ^ ((rb >> 1) & 3)) * 8);
  }
  for (int kt = 0; kt < KDIM; kt += 32) {
    stage_tile(A + kt, lda, As);
    stage_tile(Bt + kt, ldb, Bs);
    __syncthreads();
    bf16x8 af[4], bfr[4];
#pragma unroll
    for (int t = 0; t < 4; ++t) af[t] = *(const bf16x8*)(As + aoff[t]);
#pragma unroll
    for (int t = 0; t < 4; ++t) bfr[t] = *(const bf16x8*)(Bs + boff[t]);
#pragma unroll
    for (int mt = 0; mt < 4; ++mt)
#pragma unroll
      for (int nt = 0; nt < 4; ++nt)
        acc[mt][nt] = __builtin_amdgcn_mfma_f32_16x16x32_bf16(af[mt], bfr[nt], acc[mt][nt], 0, 0, 0);
    __syncthreads();
  }
}

// ---------------- GEMM1: h1 = gelu(disp @ w1 + b1), bf16 out -------------------------
__global__ __launch_bounds__(256, 2) void gemm1_kernel(const u16* __restrict__ disp,
                                                       const u16* __restrict__ w1t,
                                                       const float* __restrict__ b1,
                                                       u16* __restrict__ h1) {
  __shared__ __align__(16) u16 As[4096];
  __shared__ __align__(16) u16 Bs[4096];
  int e = blockIdx.z;
  int m0 = blockIdx.y * 128, n0 = blockIdx.x * 128;
  const u16* A  = disp + (size_t)e * CAP * H_DIM + (size_t)m0 * H_DIM;
  const u16* Bt = w1t + (size_t)e * DFF * H_DIM + (size_t)n0 * H_DIM;
  f32x4 acc[4][4];
  f32x4 zero = {0.f, 0.f, 0.f, 0.f};
#pragma unroll
  for (int i = 0; i < 4; ++i)
#pragma unroll
    for (int j = 0; j < 4; ++j) acc[i][j] = zero;
  gemm_core<H_DIM>(A, Bt, H_DIM, H_DIM, As, Bs, acc);
  int tid = threadIdx.x, lane = tid & 63, w = tid >> 6, wm = w >> 1, wn = w & 1;
  int q = lane >> 4, l15 = lane & 15;
  const float* b1e = b1 + e * DFF;
  u16* out = h1 + (size_t)e * CAP * DFF;
#pragma unroll
  for (int mt = 0; mt < 4; ++mt)
#pragma unroll
    for (int nt = 0; nt < 4; ++nt) {
      int col = n0 + wn * 64 + nt * 16 + l15;
      float bias = b1e[col];
#pragma unroll
      for (int r = 0; r < 4; ++r) {
        int row = m0 + wm * 64 + mt * 16 + q * 4 + r;
        out[(size_t)row * DFF + col] = f2bf(gelu_tanh(acc[mt][nt][r] + bias));
      }
    }
}

// ---------------- GEMM2: eo = h1 @ w2 + b2, fused gate-weighted scatter --------------
__global__ __launch_bounds__(256, 2) void gemm2_kernel(const u16* __restrict__ h1,
                                                       const u16* __restrict__ w2t,
                                                       const float* __restrict__ b2,
                                                       const int* __restrict__ slot_token,
                                                       const float* __restrict__ gate,
                                                       const int* __restrict__ counts,
                                                       float* __restrict__ out) {
  __shared__ __align__(16) u16 As[4096];
  __shared__ __align__(16) u16 Bs[4096];
  int e = blockIdx.z;
  int m0 = blockIdx.y * 128, n0 = blockIdx.x * 128;
  const u16* A  = h1 + (size_t)e * CAP * DFF + (size_t)m0 * DFF;
  const u16* Bt = w2t + (size_t)e * H_DIM * DFF + (size_t)n0 * DFF;
  f32x4 acc[4][4];
  f32x4 zero = {0.f, 0.f, 0.f, 0.f};
#pragma unroll
  for (int i = 0; i < 4; ++i)
#pragma unroll
    for (int j = 0; j < 4; ++j) acc[i][j] = zero;
  gemm_core<DFF>(A, Bt, DFF, DFF, As, Bs, acc);
  int tid = threadIdx.x, lane = tid & 63, w = tid >> 6, wm = w >> 1, wn = w & 1;
  int q = lane >> 4, l15 = lane & 15;
  int cnt = counts[e];
  const float* b2e = b2 + e * H_DIM;
#pragma unroll
  for (int mt = 0; mt < 4; ++mt) {
    int tok[4]; float gv[4];
#pragma unroll
    for (int r = 0; r < 4; ++r) {
      int c = m0 + wm * 64 + mt * 16 + q * 4 + r;
      if (c < cnt) { int s = slot_token[e * CAP + c]; tok[r] = s; gv[r] = gate[s]; }
      else { tok[r] = -1; gv[r] = 0.f; }
    }
#pragma unroll
    for (int nt = 0; nt < 4; ++nt) {
      int col = n0 + wn * 64 + nt * 16 + l15;
      float bias = b2e[col];
#pragma unroll
      for (int r = 0; r < 4; ++r)
        if (tok[r] >= 0)
          out[(size_t)tok[r] * H_DIM + col] = gv[r] * (acc[mt][nt][r] + bias);
    }
  }
}

extern "C" void kernel_launch(void* const* d_in, const int* in_sizes, int n_in,
                              void* d_out, int out_size, void* d_ws, size_t ws_size,
                              hipStream_t stream) {
  const float* x  = (const float*)d_in[0];
  const float* wg = (const float*)d_in[1];
  const float* w1 = (const float*)d_in[2];
  const float* b1 = (const float*)d_in[3];
  const float* w2 = (const float*)d_in[4];
  const float* b2 = (const float*)d_in[5];
  float* out = (float*)d_out;
  char* ws = (char*)d_ws;
  const size_t MB = 1024 * 1024;
  // ws layout: w1t 64MB | w2t 64MB | disp 16MB | h1 64MB | small buffers (~200KB)
  u16* w1t  = (u16*)(ws);
  u16* w2t  = (u16*)(ws + 64 * MB);
  u16* disp = (u16*)(ws + 128 * MB);
  u16* h1   = (u16*)(ws + 144 * MB);
  char* sm = ws + 208 * MB;
  float* gate      = (float*)(sm);
  int*   expert    = (int*)(sm + 32 * 1024);
  int*   rank      = (int*)(sm + 64 * 1024);
  int*   slot_tok  = (int*)(sm + 96 * 1024);
  int*   blockCnt  = (int*)(sm + 128 * 1024);
  int*   blockOff  = (int*)(sm + 144 * 1024);
  float* blockMe   = (float*)(sm + 160 * 1024);
  int*   counts    = (int*)(sm + 176 * 1024);

  hipMemsetAsync(d_out, 0, (size_t)out_size * sizeof(float), stream);
  gate_kernel<<<512, 256, 0, stream>>>(x, wg, gate, expert, rank, blockCnt, blockMe);
  scan_kernel<<<1, 512, 0, stream>>>(blockCnt, blockMe, blockOff, counts,
                                     out + (size_t)S_TOK * H_DIM);
  assign_kernel<<<32, 256, 0, stream>>>(expert, rank, blockOff, slot_tok);
  gather_kernel<<<8192, 256, 0, stream>>>(x, slot_tok, counts, disp);
  transpose_convert<<<dim3(DFF / 32, H_DIM / 32, NE), 256, 0, stream>>>(w1, w1t, H_DIM, DFF);
  transpose_convert<<<dim3(H_DIM / 32, DFF / 32, NE), 256, 0, stream>>>(w2, w2t, DFF, H_DIM);
  gemm1_kernel<<<dim3(DFF / 128, CAP / 128, NE), 256, 0, stream>>>(disp, w1t, b1, h1);
  gemm2_kernel<<<dim3(H_DIM / 128, CAP / 128, NE), 256, 0, stream>>>(h1, w2t, b2,
                                                                     slot_tok, gate, counts, out);
}

// Round 3
// 616.469 us; speedup vs baseline: 1.0236x; 1.0236x over previous
//
#include <hip/hip_runtime.h>

#define S_TOK 8192
#define H_DIM 1024
#define NE    8
#define CAP   1024
#define DFF   4096

typedef unsigned short u16;
typedef __bf16 bf16_t;
typedef bf16_t bf16x8 __attribute__((ext_vector_type(8)));
typedef float  f32x4  __attribute__((ext_vector_type(4)));

__device__ __forceinline__ u16 f2bf(float f) {
  union { float f; unsigned u; } a; a.f = f;
  unsigned u = a.u;
  u += 0x7fffu + ((u >> 16) & 1u);   // RNE
  return (u16)(u >> 16);
}

__device__ __forceinline__ float gelu_tanh(float x) {
  const float c = 0.7978845608028654f;
  float t = tanhf(c * (x + 0.044715f * x * x * x));
  return 0.5f * x * (1.0f + t);
}

// ---------------- gating: logits, softmax, argmax, per-block rank/histogram ----------
__global__ void gate_kernel(const float* __restrict__ x, const float* __restrict__ wg,
                            float* __restrict__ gate, int* __restrict__ expert,
                            int* __restrict__ rank, int* __restrict__ blockCnt,
                            float* __restrict__ blockMe) {
  __shared__ float sg[16][8];
  __shared__ int   se[16];
  int tid = threadIdx.x, lane = tid & 63, w = tid >> 6;
  int b = blockIdx.x;
  for (int j = 0; j < 4; ++j) {
    int t = w * 4 + j;
    int s = b * 16 + t;
    const float* xr = x + (size_t)s * H_DIM;
    float acc[8];
#pragma unroll
    for (int e = 0; e < 8; ++e) acc[e] = 0.f;
#pragma unroll
    for (int i = 0; i < 16; ++i) {
      int h = i * 64 + lane;
      float xv = xr[h];
      float4 wa = *(const float4*)(wg + h * 8);
      float4 wb = *(const float4*)(wg + h * 8 + 4);
      acc[0] += xv * wa.x; acc[1] += xv * wa.y; acc[2] += xv * wa.z; acc[3] += xv * wa.w;
      acc[4] += xv * wb.x; acc[5] += xv * wb.y; acc[6] += xv * wb.z; acc[7] += xv * wb.w;
    }
#pragma unroll
    for (int off = 32; off >= 1; off >>= 1)
#pragma unroll
      for (int e = 0; e < 8; ++e) acc[e] += __shfl_down(acc[e], off);
    if (lane == 0) {
      float mx = acc[0];
#pragma unroll
      for (int e = 1; e < 8; ++e) mx = fmaxf(mx, acc[e]);
      float g[8], Z = 0.f;
#pragma unroll
      for (int e = 0; e < 8; ++e) { g[e] = expf(acc[e] - mx); Z += g[e]; }
      int am = 0; float best = acc[0];
#pragma unroll
      for (int e = 1; e < 8; ++e) if (acc[e] > best) { best = acc[e]; am = e; }
      float inv = 1.f / Z;
#pragma unroll
      for (int e = 0; e < 8; ++e) sg[t][e] = g[e] * inv;
      se[t] = am;
      gate[s] = g[am] * inv;
      expert[s] = am;
    }
  }
  __syncthreads();
  if (tid < 16) {
    int e = se[tid], r = 0;
    for (int t2 = 0; t2 < tid; ++t2) r += (se[t2] == e) ? 1 : 0;
    rank[b * 16 + tid] = r;
  }
  if (tid < 8) {
    int c = 0; float m = 0.f;
#pragma unroll
    for (int t = 0; t < 16; ++t) { c += (se[t] == tid) ? 1 : 0; m += sg[t][tid]; }
    blockCnt[b * 8 + tid] = c;
    blockMe[b * 8 + tid] = m;
  }
}

// ------------- scan over 512 block histograms; l_aux + exp_counts to out tail --------
__global__ void scan_kernel(const int* __restrict__ blockCnt, const float* __restrict__ blockMe,
                            int* __restrict__ blockOff, int* __restrict__ counts,
                            float* __restrict__ tail) {
  int tid = threadIdx.x;
  int e = tid >> 6, lane = tid & 63;   // one wave per expert
  int run = 0; float msum = 0.f;
  for (int c = 0; c < 8; ++c) {
    int b = c * 64 + lane;
    int v = blockCnt[b * 8 + e];
    float mv = blockMe[b * 8 + e];
    int sc = v;
#pragma unroll
    for (int off = 1; off < 64; off <<= 1) {
      int u = __shfl_up(sc, off);
      if (lane >= off) sc += u;
    }
    blockOff[b * 8 + e] = run + sc - v;
    run += __shfl(sc, 63);
#pragma unroll
    for (int off = 32; off >= 1; off >>= 1) mv += __shfl_down(mv, off);
    msum += __shfl(mv, 0);
  }
  __shared__ float sm[8];
  __shared__ int scnt[8];
  if (lane == 0) {
    sm[e] = msum; scnt[e] = run;
    counts[e] = run < CAP ? run : CAP;
  }
  __syncthreads();
  if (tid == 0) {
    float la = 0.f;
    for (int i = 0; i < 8; ++i)
      la += (sm[i] / (float)S_TOK) * ((float)scnt[i] / (float)S_TOK);
    tail[0] = la * (float)NE;
    for (int i = 0; i < 8; ++i) {
      int cc = scnt[i] < CAP ? scnt[i] : CAP;
      tail[1 + i] = (float)cc;
    }
  }
}

// ---------------- slot assignment ----------------------------------------------------
__global__ void assign_kernel(const int* __restrict__ expert, const int* __restrict__ rank,
                              const int* __restrict__ blockOff, int* __restrict__ slot_token) {
  int s = blockIdx.x * 256 + threadIdx.x;
  int e = expert[s];
  int pos = blockOff[(s >> 4) * 8 + e] + rank[s];
  if (pos < CAP) slot_token[e * CAP + pos] = s;
}

// ---------------- gather tokens into expert slots (fp32 -> bf16) ---------------------
__global__ void gather_kernel(const float* __restrict__ x, const int* __restrict__ slot_token,
                              const int* __restrict__ counts, u16* __restrict__ disp) {
  int slot = blockIdx.x;
  int e = slot >> 10, c = slot & 1023;
  int t = threadIdx.x;
  ushort4 v4;
  if (c < counts[e]) {
    int s = slot_token[slot];
    float4 v = *(const float4*)(x + (size_t)s * H_DIM + t * 4);
    v4.x = f2bf(v.x); v4.y = f2bf(v.y); v4.z = f2bf(v.z); v4.w = f2bf(v.w);
  } else {
    v4.x = 0; v4.y = 0; v4.z = 0; v4.w = 0;
  }
  *(ushort4*)(disp + (size_t)slot * H_DIM + t * 4) = v4;
}

// ---------------- transpose + fp32->bf16 convert: src[R][C] -> dst[C][R] -------------
// 64x64 tile, 256 threads. LDS stride 65 (2-way banks both phases, free per m136).
// Stores: 16 lanes x ushort4 = 128 B contiguous segments.
__global__ void transpose_convert(const float* __restrict__ src0, u16* __restrict__ dst0,
                                  int R, int C) {
  __shared__ float tile[64][65];
  int e = blockIdx.z;
  const float* src = src0 + (size_t)e * R * C;
  u16* dst = dst0 + (size_t)e * R * C;
  int c0 = blockIdx.x * 64, r0 = blockIdx.y * 64;
  int g = threadIdx.x & 15, rr = threadIdx.x >> 4;
#pragma unroll
  for (int p = 0; p < 4; ++p) {
    int r = rr + p * 16;
    float4 v = *(const float4*)(src + (size_t)(r0 + r) * C + c0 + g * 4);
    tile[r][g * 4 + 0] = v.x;
    tile[r][g * 4 + 1] = v.y;
    tile[r][g * 4 + 2] = v.z;
    tile[r][g * 4 + 3] = v.w;
  }
  __syncthreads();
#pragma unroll
  for (int p = 0; p < 4; ++p) {
    int c = rr + p * 16;
    ushort4 o;
    o.x = f2bf(tile[g * 4 + 0][c]);
    o.y = f2bf(tile[g * 4 + 1][c]);
    o.z = f2bf(tile[g * 4 + 2][c]);
    o.w = f2bf(tile[g * 4 + 3][c]);
    *(ushort4*)(dst + (size_t)(c0 + c) * R + r0 + g * 4) = o;
  }
}

// ---------------- GEMM core (256-thread / 4-wave, m97 structure) ---------------------
// LDS layout: per tile row (32 bf16 = 4 x 16B chunks), chunk slot = kq ^ ((row>>1)&3)
__device__ __forceinline__ void stage_tile(const u16* g, int ldk, u16* lds) {
  int tid = threadIdx.x;
  int lane = tid & 63, w = tid >> 6;
#pragma unroll
  for (int r = 0; r < 2; ++r) {
    int p = (w * 2 + r) * 64 + lane;      // physical 16B chunk 0..511
    int row = p >> 2;
    int kq = (p & 3) ^ ((row >> 1) & 3);  // logical k-chunk stored at this slot
    const u16* gp = g + (size_t)row * ldk + kq * 8;
    u16* lp = lds + (w * 2 + r) * 512;    // wave-uniform base; HW adds lane*16B
    __builtin_amdgcn_global_load_lds((__attribute__((address_space(1))) int*)(gp),
                                     (__attribute__((address_space(3))) int*)(lp),
                                     16, 0, 0);
  }
}

template <int KDIM>
__device__ __forceinline__ void gemm_core(const u16* A, const u16* Bt, int lda, int ldb,
                                          u16* As, u16* Bs, f32x4 acc[4][4]) {
  int tid = threadIdx.x;
  int lane = tid & 63;
  int w = tid >> 6, wm = w >> 1, wn = w & 1;
  int q = lane >> 4, l15 = lane & 15;
  int aoff[4], boff[4];
#pragma unroll
  for (int t = 0; t < 4; ++t) {
    int ra = wm * 64 + t * 16 + l15;
    aoff[t] = ra * 32 + ((q ^ ((ra >> 1) & 3)) * 8);
    int rb = wn * 64 + t * 16 + l15;
    boff[t] = rb * 32 + ((q ^ ((rb >> 1) & 3)) * 8);
  }
  for (int kt = 0; kt < KDIM; kt += 32) {
    stage_tile(A + kt, lda, As);
    stage_tile(Bt + kt, ldb, Bs);
    __syncthreads();
    bf16x8 af[4], bfr[4];
#pragma unroll
    for (int t = 0; t < 4; ++t) af[t] = *(const bf16x8*)(As + aoff[t]);
#pragma unroll
    for (int t = 0; t < 4; ++t) bfr[t] = *(const bf16x8*)(Bs + boff[t]);
#pragma unroll
    for (int mt = 0; mt < 4; ++mt)
#pragma unroll
      for (int nt = 0; nt < 4; ++nt)
        acc[mt][nt] = __builtin_amdgcn_mfma_f32_16x16x32_bf16(af[mt], bfr[nt], acc[mt][nt], 0, 0, 0);
    __syncthreads();
  }
}

// ---------------- GEMM1: h1 = gelu(disp @ w1 + b1), bf16 out -------------------------
__global__ __launch_bounds__(256, 2) void gemm1_kernel(const u16* __restrict__ disp,
                                                       const u16* __restrict__ w1t,
                                                       const float* __restrict__ b1,
                                                       u16* __restrict__ h1) {
  __shared__ __align__(16) u16 As[4096];
  __shared__ __align__(16) u16 Bs[4096];
  int e = blockIdx.z;
  int m0 = blockIdx.y * 128, n0 = blockIdx.x * 128;
  const u16* A  = disp + (size_t)e * CAP * H_DIM + (size_t)m0 * H_DIM;
  const u16* Bt = w1t + (size_t)e * DFF * H_DIM + (size_t)n0 * H_DIM;
  f32x4 acc[4][4];
  f32x4 zero = {0.f, 0.f, 0.f, 0.f};
#pragma unroll
  for (int i = 0; i < 4; ++i)
#pragma unroll
    for (int j = 0; j < 4; ++j) acc[i][j] = zero;
  gemm_core<H_DIM>(A, Bt, H_DIM, H_DIM, As, Bs, acc);
  int tid = threadIdx.x, lane = tid & 63, w = tid >> 6, wm = w >> 1, wn = w & 1;
  int q = lane >> 4, l15 = lane & 15;
  const float* b1e = b1 + e * DFF;
  u16* out = h1 + (size_t)e * CAP * DFF;
#pragma unroll
  for (int mt = 0; mt < 4; ++mt)
#pragma unroll
    for (int nt = 0; nt < 4; ++nt) {
      int col = n0 + wn * 64 + nt * 16 + l15;
      float bias = b1e[col];
#pragma unroll
      for (int r = 0; r < 4; ++r) {
        int row = m0 + wm * 64 + mt * 16 + q * 4 + r;
        out[(size_t)row * DFF + col] = f2bf(gelu_tanh(acc[mt][nt][r] + bias));
      }
    }
}

// ---------------- GEMM2: 512-thread / 8-wave blocks (wave tile 64x32) ----------------
// grid is only 512 blocks (2/CU); 8 waves/block doubles resident waves to 16/CU.
// Staging: waves 0-3 stage A (2 chunks/thread = 512 chunks), waves 4-7 stage B.
__global__ __launch_bounds__(512, 4) void gemm2_kernel(const u16* __restrict__ h1,
                                                       const u16* __restrict__ w2t,
                                                       const float* __restrict__ b2,
                                                       const int* __restrict__ slot_token,
                                                       const float* __restrict__ gate,
                                                       const int* __restrict__ counts,
                                                       float* __restrict__ out) {
  __shared__ __align__(16) u16 As[4096];
  __shared__ __align__(16) u16 Bs[4096];
  int e = blockIdx.z;
  int m0 = blockIdx.y * 128, n0 = blockIdx.x * 128;
  const u16* A  = h1 + (size_t)e * CAP * DFF + (size_t)m0 * DFF;
  const u16* Bt = w2t + (size_t)e * H_DIM * DFF + (size_t)n0 * DFF;
  int tid = threadIdx.x, lane = tid & 63, w = tid >> 6;
  int wm = w >> 2, wn = w & 3;           // wave grid 2(m) x 4(n)
  int q = lane >> 4, l15 = lane & 15;
  f32x4 acc[4][2];
  f32x4 zero = {0.f, 0.f, 0.f, 0.f};
#pragma unroll
  for (int i = 0; i < 4; ++i) { acc[i][0] = zero; acc[i][1] = zero; }

  // staging: 2 chunks per thread -> full 512-chunk (8 KB) tile per operand
  const u16* gsrc = (w < 4) ? A : Bt;
  u16* ldst = (w < 4) ? As : Bs;
  int q4 = w & 3;
  const u16* gp0[2]; u16* lp[2];
#pragma unroll
  for (int r = 0; r < 2; ++r) {
    int p = (q4 * 2 + r) * 64 + lane;    // 16B chunk 0..511 within the tile
    int srow = p >> 2;
    int skq = (p & 3) ^ ((srow >> 1) & 3);
    gp0[r] = gsrc + (size_t)srow * DFF + skq * 8;
    lp[r] = ldst + (q4 * 2 + r) * 512;   // wave-uniform base
  }

  int aoff[4], boff[2];
#pragma unroll
  for (int t = 0; t < 4; ++t) {
    int ra = wm * 64 + t * 16 + l15;
    aoff[t] = ra * 32 + ((q ^ ((ra >> 1) & 3)) * 8);
  }
#pragma unroll
  for (int t = 0; t < 2; ++t) {
    int rb = wn * 32 + t * 16 + l15;
    boff[t] = rb * 32 + ((q ^ ((rb >> 1) & 3)) * 8);
  }

  for (int kt = 0; kt < DFF; kt += 32) {
#pragma unroll
    for (int r = 0; r < 2; ++r)
      __builtin_amdgcn_global_load_lds((__attribute__((address_space(1))) int*)(gp0[r] + kt),
                                       (__attribute__((address_space(3))) int*)(lp[r]),
                                       16, 0, 0);
    __syncthreads();
    bf16x8 af[4], bfr[2];
#pragma unroll
    for (int t = 0; t < 4; ++t) af[t] = *(const bf16x8*)(As + aoff[t]);
#pragma unroll
    for (int t = 0; t < 2; ++t) bfr[t] = *(const bf16x8*)(Bs + boff[t]);
#pragma unroll
    for (int mt = 0; mt < 4; ++mt)
#pragma unroll
      for (int nt = 0; nt < 2; ++nt)
        acc[mt][nt] = __builtin_amdgcn_mfma_f32_16x16x32_bf16(af[mt], bfr[nt], acc[mt][nt], 0, 0, 0);
    __syncthreads();
  }

  int cnt = counts[e];
  const float* b2e = b2 + e * H_DIM;
#pragma unroll
  for (int mt = 0; mt < 4; ++mt) {
    int tok[4]; float gv[4];
#pragma unroll
    for (int r = 0; r < 4; ++r) {
      int c = m0 + wm * 64 + mt * 16 + q * 4 + r;
      if (c < cnt) { int s = slot_token[e * CAP + c]; tok[r] = s; gv[r] = gate[s]; }
      else { tok[r] = -1; gv[r] = 0.f; }
    }
#pragma unroll
    for (int nt = 0; nt < 2; ++nt) {
      int col = n0 + wn * 32 + nt * 16 + l15;
      float bias = b2e[col];
#pragma unroll
      for (int r = 0; r < 4; ++r)
        if (tok[r] >= 0)
          out[(size_t)tok[r] * H_DIM + col] = gv[r] * (acc[mt][nt][r] + bias);
    }
  }
}

extern "C" void kernel_launch(void* const* d_in, const int* in_sizes, int n_in,
                              void* d_out, int out_size, void* d_ws, size_t ws_size,
                              hipStream_t stream) {
  const float* x  = (const float*)d_in[0];
  const float* wg = (const float*)d_in[1];
  const float* w1 = (const float*)d_in[2];
  const float* b1 = (const float*)d_in[3];
  const float* w2 = (const float*)d_in[4];
  const float* b2 = (const float*)d_in[5];
  float* out = (float*)d_out;
  char* ws = (char*)d_ws;
  const size_t MB = 1024 * 1024;
  // ws layout: w1t 64MB | w2t 64MB | disp 16MB | h1 64MB | small buffers (~200KB)
  u16* w1t  = (u16*)(ws);
  u16* w2t  = (u16*)(ws + 64 * MB);
  u16* disp = (u16*)(ws + 128 * MB);
  u16* h1   = (u16*)(ws + 144 * MB);
  char* sm = ws + 208 * MB;
  float* gate      = (float*)(sm);
  int*   expert    = (int*)(sm + 32 * 1024);
  int*   rank      = (int*)(sm + 64 * 1024);
  int*   slot_tok  = (int*)(sm + 96 * 1024);
  int*   blockCnt  = (int*)(sm + 128 * 1024);
  int*   blockOff  = (int*)(sm + 144 * 1024);
  float* blockMe   = (float*)(sm + 160 * 1024);
  int*   counts    = (int*)(sm + 176 * 1024);

  hipMemsetAsync(d_out, 0, (size_t)out_size * sizeof(float), stream);
  gate_kernel<<<512, 256, 0, stream>>>(x, wg, gate, expert, rank, blockCnt, blockMe);
  scan_kernel<<<1, 512, 0, stream>>>(blockCnt, blockMe, blockOff, counts,
                                     out + (size_t)S_TOK * H_DIM);
  assign_kernel<<<32, 256, 0, stream>>>(expert, rank, blockOff, slot_tok);
  gather_kernel<<<8192, 256, 0, stream>>>(x, slot_tok, counts, disp);
  transpose_convert<<<dim3(DFF / 64, H_DIM / 64, NE), 256, 0, stream>>>(w1, w1t, H_DIM, DFF);
  transpose_convert<<<dim3(H_DIM / 64, DFF / 64, NE), 256, 0, stream>>>(w2, w2t, DFF, H_DIM);
  gemm1_kernel<<<dim3(DFF / 128, CAP / 128, NE), 256, 0, stream>>>(disp, w1t, b1, h1);
  gemm2_kernel<<<dim3(H_DIM / 128, CAP / 128, NE), 512, 0, stream>>>(h1, w2t, b2,
                                                                     slot_tok, gate, counts, out);
}